// Round 5
// baseline (526.603 us; speedup 1.0000x reference)
//
#include <hip/hip_runtime.h>

// Problem constants (fixed by the reference setup_inputs)
#define BB 4
#define CC 64
#define HH 512
#define WW 512
#define NN 2048
// slots = B * (H/16) * (W/16) = 4 * 32 * 32
#define SLOTS 4096
#define CAP 16          // bucket capacity per slot (P(overflow) ~ 1e-18 for Poisson(0.5))

// Native clang vector type: required by __builtin_nontemporal_load/store
// (HIP's float4 is a class and is rejected).
typedef float vf4 __attribute__((ext_vector_type(4)));

// d_ws layout (ints): lst[SLOTS*CAP], cnts[SLOTS], heads[SLOTS], nxt[NN]

// ---- Fused prelude: init, detect index dtype, build per-slot buckets ----
// Single block of 1024 threads; __syncthreads orders the phases. Bucket
// counters and overflow-chain heads live in LDS; written to ws at the end.
__global__ __launch_bounds__(1024) void prelude_kernel(const int* __restrict__ idx,
                                                       int* __restrict__ lst,
                                                       int* __restrict__ cnts,
                                                       int* __restrict__ heads,
                                                       int* __restrict__ nxt) {
    __shared__ int s_cnt[SLOTS];
    __shared__ int s_head[SLOTS];
    __shared__ int s_is64;
    const int t = threadIdx.x;
    if (t == 0) s_is64 = 1;   // assume int64 until proven otherwise

    for (int i = t; i < SLOTS; i += 1024) { s_cnt[i] = 0; s_head[i] = -1; }
    __syncthreads();

    // dtype detect: if indices are int64 (little-endian, values < 512), every
    // odd int32 word is zero. int32 indices can't have all odd words zero.
    for (int i = t; i < 3 * NN / 2; i += 1024) {
        if (idx[2 * i + 1] != 0) s_is64 = 0;
    }
    __syncthreads();

    const bool is64 = (s_is64 != 0);
    for (int n = t; n < NN; n += 1024) {
        int b, hi, wi;
        if (is64) {            // int64 indices: stride 2 words, low word
            b  = idx[6 * n + 0];
            hi = idx[6 * n + 2];
            wi = idx[6 * n + 4];
        } else {               // int32 indices
            b  = idx[3 * n + 0];
            hi = idx[3 * n + 1];
            wi = idx[3 * n + 2];
        }
        const int slot = (b << 10) | (hi << 5) | wi;   // b*1024 + hi*32 + wi
        const int pos  = atomicAdd(&s_cnt[slot], 1);
        if (pos < CAP) lst[(slot << 4) + pos] = n;                 // bucket
        else           nxt[n] = atomicExch(&s_head[slot], n);      // overflow chain
    }
    __syncthreads();

    for (int i = t; i < SLOTS; i += 1024) { cnts[i] = s_cnt[i]; heads[i] = s_head[i]; }
}

// One thread per output float4. out = in + sum of covering patches.
// Buckets (no pointer chase) + minimal VGPR footprint: __launch_bounds__(256,8)
// keeps VGPR <= 64 so 8 waves/SIMD stay resident — streaming BW needs waves.
__global__ __launch_bounds__(256, 8) void scatter_add_kernel(
    const vf4* __restrict__ in4,
    const vf4* __restrict__ g4,
    const int* __restrict__ lst,
    const int* __restrict__ cnts,
    const int* __restrict__ heads,
    const int* __restrict__ nxt,
    vf4* __restrict__ out4)
{
    const int e  = blockIdx.x * 256 + threadIdx.x;  // e < B*C*H*(W/4) = 16,777,216
    const int w4 = e & 127;                         // W/4 = 128
    const int h  = (e >> 7) & 511;
    const int cb = e >> 16;                         // c + C*b
    const int c  = cb & 63;
    const int b  = cb >> 6;

    const int slot = (b << 10) | ((h >> 4) << 5) | (w4 >> 2);
    const int cnt  = cnts[slot];                    // L1-hot 16 KB table

    vf4 v = __builtin_nontemporal_load(&in4[e]);

    if (cnt > 0) {
        // gathered float4 index: n*4096 + c*64 + (h%16)*4 + (w4%4)
        const int goff  = (c << 6) | ((h & 15) << 2) | (w4 & 3);
        const int lbase = slot << 4;
        const int cnt16 = cnt < CAP ? cnt : CAP;
        int i = 0;
        for (; i + 2 <= cnt16; i += 2) {            // pairs: 2 independent loads
            const int n0 = lst[lbase + i];
            const int n1 = lst[lbase + i + 1];
            const vf4 a0 = __builtin_nontemporal_load(g4 + ((n0 << 12) + goff));
            const vf4 a1 = __builtin_nontemporal_load(g4 + ((n1 << 12) + goff));
            v += a0 + a1;
        }
        if (i < cnt16) {                            // odd tail (cnt==1 is 77% of covered)
            const int n0 = lst[lbase + i];
            v += __builtin_nontemporal_load(g4 + ((n0 << 12) + goff));
        }
        if (cnt > CAP) {                            // never expected; correctness only
            int n = heads[slot];
            while (n >= 0) {
                v += *(g4 + ((n << 12) + goff));
                n = nxt[n];
            }
        }
    }

    __builtin_nontemporal_store(v, &out4[e]);
}

// ---- Fallback path (only if d_ws is impossibly small): copy + atomic scatter ----
__global__ __launch_bounds__(256) void copy_kernel(const vf4* __restrict__ in4,
                                                   vf4* __restrict__ out4) {
    int e = blockIdx.x * 256 + threadIdx.x;
    out4[e] = in4[e];
}

__global__ __launch_bounds__(256) void atomic_scatter_kernel(
    const float* __restrict__ g,
    const int* __restrict__ idx,
    float* __restrict__ out)
{
    int i = blockIdx.x * 256 + threadIdx.x;      // i < N*C*16*16 = 33,554,432
    int n = i >> 14;                             // / 16384
    int r = i & 16383;
    int c  = r >> 8;
    int rr = (r >> 4) & 15;
    int w  = r & 15;
    int b  = idx[3 * n + 0];
    int hi = idx[3 * n + 1];
    int wi = idx[3 * n + 2];
    int off = ((b * CC + c) * HH + hi * 16 + rr) * WW + wi * 16 + w;
    atomicAdd(&out[off], g[i]);
}

extern "C" void kernel_launch(void* const* d_in, const int* in_sizes, int n_in,
                              void* d_out, int out_size, void* d_ws, size_t ws_size,
                              hipStream_t stream) {
    const float* inp      = (const float*)d_in[0];
    const float* gathered = (const float*)d_in[1];
    const int*   idx      = (const int*)d_in[2];
    float* out = (float*)d_out;

    const size_t ws_needed = (size_t)(SLOTS * CAP + SLOTS + SLOTS + NN) * sizeof(int);

    if (ws_size >= ws_needed) {
        int* lst   = (int*)d_ws;           // 64 B-aligned, SLOTS*CAP ints
        int* cnts  = lst + SLOTS * CAP;
        int* heads = cnts + SLOTS;
        int* nxt   = heads + SLOTS;
        prelude_kernel<<<1, 1024, 0, stream>>>(idx, lst, cnts, heads, nxt);
        const int n_out4 = BB * CC * HH * (WW / 4);        // 16,777,216
        scatter_add_kernel<<<n_out4 / 256, 256, 0, stream>>>(
            (const vf4*)inp, (const vf4*)gathered, lst, cnts, heads, nxt,
            (vf4*)out);
    } else {
        const int n_out4 = BB * CC * HH * (WW / 4);
        copy_kernel<<<n_out4 / 256, 256, 0, stream>>>((const vf4*)inp, (vf4*)out);
        const int n_g = NN * CC * 16 * 16;                 // 33,554,432
        atomic_scatter_kernel<<<n_g / 256, 256, 0, stream>>>(gathered, idx, out);
    }
}

// Round 6
// 503.822 us; speedup vs baseline: 1.0452x; 1.0452x over previous
//
#include <hip/hip_runtime.h>

// Problem constants (fixed by the reference setup_inputs)
#define BB 4
#define CC 64
#define HH 512
#define WW 512
#define NN 2048
// slots = B * (H/16) * (W/16) = 4 * 32 * 32
#define SLOTS 4096
#define CAP 16          // bucket capacity per slot (P(overflow) ~ 1e-18 for Poisson(0.5))

// Native clang vector type: required by __builtin_nontemporal_load/store
// (HIP's float4 is a class and is rejected).
typedef float vf4 __attribute__((ext_vector_type(4)));

// d_ws layout (ints): lst[SLOTS*CAP], cnts[SLOTS], heads[SLOTS], nxt[NN]

// ---- Fused prelude: init, detect index dtype, build per-slot buckets ----
// Single block of 1024 threads; __syncthreads orders the phases. Bucket
// counters and overflow-chain heads live in LDS; written to ws at the end.
__global__ __launch_bounds__(1024) void prelude_kernel(const int* __restrict__ idx,
                                                       int* __restrict__ lst,
                                                       int* __restrict__ cnts,
                                                       int* __restrict__ heads,
                                                       int* __restrict__ nxt) {
    __shared__ int s_cnt[SLOTS];
    __shared__ int s_head[SLOTS];
    __shared__ int s_is64;
    const int t = threadIdx.x;
    if (t == 0) s_is64 = 1;   // assume int64 until proven otherwise

    for (int i = t; i < SLOTS; i += 1024) { s_cnt[i] = 0; s_head[i] = -1; }
    __syncthreads();

    // dtype detect: if indices are int64 (little-endian, values < 512), every
    // odd int32 word is zero. int32 indices can't have all odd words zero.
    for (int i = t; i < 3 * NN / 2; i += 1024) {
        if (idx[2 * i + 1] != 0) s_is64 = 0;
    }
    __syncthreads();

    const bool is64 = (s_is64 != 0);
    for (int n = t; n < NN; n += 1024) {
        int b, hi, wi;
        if (is64) {            // int64 indices: stride 2 words, low word
            b  = idx[6 * n + 0];
            hi = idx[6 * n + 2];
            wi = idx[6 * n + 4];
        } else {               // int32 indices
            b  = idx[3 * n + 0];
            hi = idx[3 * n + 1];
            wi = idx[3 * n + 2];
        }
        const int slot = (b << 10) | (hi << 5) | wi;   // b*1024 + hi*32 + wi
        const int pos  = atomicAdd(&s_cnt[slot], 1);
        if (pos < CAP) lst[(slot << 4) + pos] = n;                 // bucket
        else           nxt[n] = atomicExch(&s_head[slot], n);      // overflow chain
    }
    __syncthreads();

    for (int i = t; i < SLOTS; i += 1024) { cnts[i] = s_cnt[i]; heads[i] = s_head[i]; }
}

// One thread per EIGHT output float4s (8 consecutive h rows within one slot).
// out = in + sum of covering patches. Amortizes the slot lookup + index math
// over 8 rows; each patch contributes 8 INDEPENDENT gathered loads (deep MLP).
// No forced min-waves: ~90-110 VGPR -> 4 waves/SIMD, no spills (R5 lesson).
__global__ __launch_bounds__(256) void scatter_add_kernel(
    const vf4* __restrict__ in4,
    const vf4* __restrict__ g4,
    const int* __restrict__ lst,
    const int* __restrict__ cnts,
    const int* __restrict__ heads,
    const int* __restrict__ nxt,
    vf4* __restrict__ out4)
{
    const int t  = blockIdx.x * 256 + threadIdx.x;  // t < B*C*(H/8)*(W/4) = 2,097,152
    const int w4 = t & 127;                         // W/4 = 128
    const int hq = (t >> 7) & 63;                   // h/8 in [0,64)
    const int cb = t >> 13;                         // c + C*b
    const int c  = cb & 63;
    const int b  = cb >> 6;
    const int h0 = hq << 3;                         // first of 8 h rows

    const int slot = (b << 10) | ((hq >> 1) << 5) | (w4 >> 2);
    const int cnt  = cnts[slot];                    // L2-hot 16 KB table

    const int base = (cb << 16) | (h0 << 7) | w4;   // float4 index into in/out

    vf4 v0 = __builtin_nontemporal_load(&in4[base]);
    vf4 v1 = __builtin_nontemporal_load(&in4[base + 128]);
    vf4 v2 = __builtin_nontemporal_load(&in4[base + 256]);
    vf4 v3 = __builtin_nontemporal_load(&in4[base + 384]);
    vf4 v4 = __builtin_nontemporal_load(&in4[base + 512]);
    vf4 v5 = __builtin_nontemporal_load(&in4[base + 640]);
    vf4 v6 = __builtin_nontemporal_load(&in4[base + 768]);
    vf4 v7 = __builtin_nontemporal_load(&in4[base + 896]);

    if (cnt > 0) {
        // gathered float4 index: n*4096 + c*64 + (h%16)*4 + (w4%4); rows +4 each
        const int goff  = (c << 6) | ((h0 & 15) << 2) | (w4 & 3);
        const int lbase = slot << 4;
        const int cnt16 = cnt < CAP ? cnt : CAP;
        for (int i = 0; i < cnt16; ++i) {           // 8 independent loads / patch
            const int n0 = lst[lbase + i];
            const vf4* __restrict__ gp = g4 + ((n0 << 12) + goff);
            const vf4 a0 = __builtin_nontemporal_load(gp + 0);
            const vf4 a1 = __builtin_nontemporal_load(gp + 4);
            const vf4 a2 = __builtin_nontemporal_load(gp + 8);
            const vf4 a3 = __builtin_nontemporal_load(gp + 12);
            const vf4 a4 = __builtin_nontemporal_load(gp + 16);
            const vf4 a5 = __builtin_nontemporal_load(gp + 20);
            const vf4 a6 = __builtin_nontemporal_load(gp + 24);
            const vf4 a7 = __builtin_nontemporal_load(gp + 28);
            v0 += a0; v1 += a1; v2 += a2; v3 += a3;
            v4 += a4; v5 += a5; v6 += a6; v7 += a7;
        }
        if (cnt > CAP) {                            // never expected; correctness only
            int n = heads[slot];
            while (n >= 0) {
                const vf4* __restrict__ gp = g4 + ((n << 12) + goff);
                v0 += gp[0];  v1 += gp[4];  v2 += gp[8];  v3 += gp[12];
                v4 += gp[16]; v5 += gp[20]; v6 += gp[24]; v7 += gp[28];
                n = nxt[n];
            }
        }
    }

    __builtin_nontemporal_store(v0, &out4[base]);
    __builtin_nontemporal_store(v1, &out4[base + 128]);
    __builtin_nontemporal_store(v2, &out4[base + 256]);
    __builtin_nontemporal_store(v3, &out4[base + 384]);
    __builtin_nontemporal_store(v4, &out4[base + 512]);
    __builtin_nontemporal_store(v5, &out4[base + 640]);
    __builtin_nontemporal_store(v6, &out4[base + 768]);
    __builtin_nontemporal_store(v7, &out4[base + 896]);
}

// ---- Fallback path (only if d_ws is impossibly small): copy + atomic scatter ----
__global__ __launch_bounds__(256) void copy_kernel(const vf4* __restrict__ in4,
                                                   vf4* __restrict__ out4) {
    int e = blockIdx.x * 256 + threadIdx.x;
    out4[e] = in4[e];
}

__global__ __launch_bounds__(256) void atomic_scatter_kernel(
    const float* __restrict__ g,
    const int* __restrict__ idx,
    float* __restrict__ out)
{
    int i = blockIdx.x * 256 + threadIdx.x;      // i < N*C*16*16 = 33,554,432
    int n = i >> 14;                             // / 16384
    int r = i & 16383;
    int c  = r >> 8;
    int rr = (r >> 4) & 15;
    int w  = r & 15;
    int b  = idx[3 * n + 0];
    int hi = idx[3 * n + 1];
    int wi = idx[3 * n + 2];
    int off = ((b * CC + c) * HH + hi * 16 + rr) * WW + wi * 16 + w;
    atomicAdd(&out[off], g[i]);
}

extern "C" void kernel_launch(void* const* d_in, const int* in_sizes, int n_in,
                              void* d_out, int out_size, void* d_ws, size_t ws_size,
                              hipStream_t stream) {
    const float* inp      = (const float*)d_in[0];
    const float* gathered = (const float*)d_in[1];
    const int*   idx      = (const int*)d_in[2];
    float* out = (float*)d_out;

    const size_t ws_needed = (size_t)(SLOTS * CAP + SLOTS + SLOTS + NN) * sizeof(int);

    if (ws_size >= ws_needed) {
        int* lst   = (int*)d_ws;           // 64 B-aligned, SLOTS*CAP ints
        int* cnts  = lst + SLOTS * CAP;
        int* heads = cnts + SLOTS;
        int* nxt   = heads + SLOTS;
        prelude_kernel<<<1, 1024, 0, stream>>>(idx, lst, cnts, heads, nxt);
        const int n_thr = BB * CC * (HH / 8) * (WW / 4);   // 2,097,152
        scatter_add_kernel<<<n_thr / 256, 256, 0, stream>>>(
            (const vf4*)inp, (const vf4*)gathered, lst, cnts, heads, nxt,
            (vf4*)out);
    } else {
        const int n_out4 = BB * CC * HH * (WW / 4);
        copy_kernel<<<n_out4 / 256, 256, 0, stream>>>((const vf4*)inp, (vf4*)out);
        const int n_g = NN * CC * 16 * 16;                 // 33,554,432
        atomic_scatter_kernel<<<n_g / 256, 256, 0, stream>>>(gathered, idx, out);
    }
}